// Round 1
// baseline (1021.084 us; speedup 1.0000x reference)
//
#include <hip/hip_runtime.h>

// Problem constants (fixed by the reference)
static constexpr int NN  = 50000;   // nodes
static constexpr int EE  = 800000;  // edges
static constexpr int CIN = 96;      // input channels
static constexpr int L1C = 70;      // TAG layer 1 out
static constexpr int L2C = 43;      // TAG layer 2 out
static constexpr int OC  = 16;      // GCN out channels (mu / logstd)

// ---------------------------------------------------------------- utilities

__global__ void zero_int_kernel(int* __restrict__ p, int n) {
    int i = blockIdx.x * blockDim.x + threadIdx.x;
    if (i < n) p[i] = 0;
}

__global__ void copy_int_kernel(const int* __restrict__ a, int* __restrict__ b, int n) {
    int i = blockIdx.x * blockDim.x + threadIdx.x;
    if (i < n) b[i] = a[i];
}

// in-degree histogram over col
__global__ void hist_kernel(const int* __restrict__ col, int* __restrict__ deg, int E) {
    int e = blockIdx.x * blockDim.x + threadIdx.x;
    if (e < E) atomicAdd(&deg[col[e]], 1);
}

// single-block exclusive scan (N=50000 -> 49 chunks of 1024)
__global__ void scan_kernel(const int* __restrict__ deg, int* __restrict__ off, int n) {
    __shared__ int sd[1024];
    __shared__ int carry;
    int tid = threadIdx.x;
    if (tid == 0) carry = 0;
    __syncthreads();
    for (int base = 0; base < n; base += 1024) {
        int i = base + tid;
        int v = (i < n) ? deg[i] : 0;
        sd[tid] = v;
        __syncthreads();
        for (int s = 1; s < 1024; s <<= 1) {
            int t = (tid >= s) ? sd[tid - s] : 0;
            __syncthreads();
            sd[tid] += t;
            __syncthreads();
        }
        int cbase = carry;
        __syncthreads();
        if (i < n) off[i] = cbase + sd[tid] - v;   // exclusive
        if (tid == 1023) carry = cbase + sd[1023];
        __syncthreads();
    }
    if (tid == 0) off[n] = carry;
}

// dis = deg>0 ? rsqrt(deg) : 0 ; dis2 = rsqrt(deg+1)
__global__ void dis_kernel(const int* __restrict__ deg, float* __restrict__ dis,
                           float* __restrict__ dis2, int n) {
    int i = blockIdx.x * blockDim.x + threadIdx.x;
    if (i < n) {
        int d = deg[i];
        dis[i]  = (d > 0) ? rsqrtf((float)d) : 0.0f;
        dis2[i] = rsqrtf((float)d + 1.0f);
    }
}

// place each edge into its destination bucket; store source + both edge weights
__global__ void fill_kernel(const int* __restrict__ row, const int* __restrict__ col,
                            const float* __restrict__ dis, const float* __restrict__ dis2,
                            int* __restrict__ cursor, int* __restrict__ csr_src,
                            float* __restrict__ wTag, float* __restrict__ wGcn, int E) {
    int e = blockIdx.x * blockDim.x + threadIdx.x;
    if (e < E) {
        int r = row[e], c = col[e];
        int pos = atomicAdd(&cursor[c], 1);
        csr_src[pos] = r;
        wTag[pos] = dis[r]  * dis[c];
        wGcn[pos] = dis2[r] * dis2[c];
    }
}

// ------------------------------------------------------------- aggregation
// out[i][c] = sum over incoming edges (w * in[src][c]); gather-based, no atomics.
template <int C, int VEC>
__global__ void agg_kernel(const float* __restrict__ in, float* __restrict__ out,
                           const int* __restrict__ off, const int* __restrict__ src,
                           const float* __restrict__ wgt, int n) {
    constexpr int TPN = C / VEC;          // threads per node
    int total = n * TPN;
    for (int t = blockIdx.x * blockDim.x + threadIdx.x; t < total;
         t += gridDim.x * blockDim.x) {
        int node = t / TPN;
        int cc = (t - node * TPN) * VEC;
        int beg = off[node], end = off[node + 1];
        if constexpr (VEC == 4) {
            float4 acc = make_float4(0.f, 0.f, 0.f, 0.f);
            for (int e = beg; e < end; ++e) {
                int s = src[e];
                float w = wgt[e];
                float4 v = *reinterpret_cast<const float4*>(in + s * C + cc);
                acc.x += w * v.x; acc.y += w * v.y;
                acc.z += w * v.z; acc.w += w * v.w;
            }
            *reinterpret_cast<float4*>(out + node * C + cc) = acc;
        } else {
            float2 acc = make_float2(0.f, 0.f);
            for (int e = beg; e < end; ++e) {
                int s = src[e];
                float w = wgt[e];
                float2 v = *reinterpret_cast<const float2*>(in + s * C + cc);
                acc.x += w * v.x; acc.y += w * v.y;
            }
            *reinterpret_cast<float2*>(out + node * C + cc) = acc;
        }
    }
}

// ----------------------------------------------------------------- matmul
// out[n, c] (+)= X[n, :] @ W[:, c]  ; W staged in LDS; 4-row register blocking.
template <bool INIT, bool RELU>
__global__ void mm_kernel(const float* __restrict__ X, const float* __restrict__ W,
                          const float* __restrict__ bias, float* __restrict__ out,
                          int n, int Cin, int Cout) {
    extern __shared__ float Wl[];
    for (int i = threadIdx.x; i < Cin * Cout; i += blockDim.x) Wl[i] = W[i];
    __syncthreads();
    int ntiles = (n + 3) >> 2;
    int total = ntiles * Cout;
    for (int idx = blockIdx.x * blockDim.x + threadIdx.x; idx < total;
         idx += gridDim.x * blockDim.x) {
        int tile = idx / Cout;
        int c = idx - tile * Cout;
        int n0 = tile * 4;
        if (n0 + 3 < n) {
            const float* x0 = X + (size_t)n0 * Cin;
            float a0, a1, a2, a3;
            if (INIT) { float b = bias[c]; a0 = a1 = a2 = a3 = b; }
            else {
                a0 = out[(size_t)n0 * Cout + c];
                a1 = out[(size_t)(n0 + 1) * Cout + c];
                a2 = out[(size_t)(n0 + 2) * Cout + c];
                a3 = out[(size_t)(n0 + 3) * Cout + c];
            }
            for (int k = 0; k < Cin; ++k) {
                float w = Wl[k * Cout + c];
                a0 += x0[k] * w;
                a1 += x0[Cin + k] * w;
                a2 += x0[2 * Cin + k] * w;
                a3 += x0[3 * Cin + k] * w;
            }
            if (RELU) {
                a0 = fmaxf(a0, 0.f); a1 = fmaxf(a1, 0.f);
                a2 = fmaxf(a2, 0.f); a3 = fmaxf(a3, 0.f);
            }
            out[(size_t)n0 * Cout + c] = a0;
            out[(size_t)(n0 + 1) * Cout + c] = a1;
            out[(size_t)(n0 + 2) * Cout + c] = a2;
            out[(size_t)(n0 + 3) * Cout + c] = a3;
        } else {
            for (int j = 0; j < 4 && n0 + j < n; ++j) {
                int nn = n0 + j;
                float a = INIT ? bias[c] : out[(size_t)nn * Cout + c];
                const float* x0 = X + (size_t)nn * Cin;
                for (int k = 0; k < Cin; ++k) a += x0[k] * Wl[k * Cout + c];
                if (RELU) a = fmaxf(a, 0.f);
                out[(size_t)nn * Cout + c] = a;
            }
        }
    }
}

// y[n, 0:16] = x3 @ Wmu ; y[n, 16:32] = x3 @ Wls   (bias added in final kernel)
__global__ void y_kernel(const float* __restrict__ X, const float* __restrict__ Wmu,
                         const float* __restrict__ Wls, float* __restrict__ y, int n) {
    __shared__ float Wl[L2C * 32];
    for (int i = threadIdx.x; i < L2C * 32; i += blockDim.x) {
        int k = i >> 5, c = i & 31;
        Wl[i] = (c < 16) ? Wmu[k * 16 + c] : Wls[k * 16 + (c - 16)];
    }
    __syncthreads();
    int total = n * 32;
    for (int idx = blockIdx.x * blockDim.x + threadIdx.x; idx < total;
         idx += gridDim.x * blockDim.x) {
        int nn = idx >> 5, c = idx & 31;
        const float* x0 = X + (size_t)nn * L2C;
        float acc = 0.f;
        for (int k = 0; k < L2C; ++k) acc += x0[k] * Wl[k * 32 + c];
        y[idx] = acc;
    }
}

// out = agg + dis2^2 * y + bias ; split interleaved (N,32) -> mu (N,16) ++ logstd (N,16)
__global__ void final_kernel(const float* __restrict__ agg, const float* __restrict__ y,
                             const float* __restrict__ dis2, const float* __restrict__ bmu,
                             const float* __restrict__ bls, float* __restrict__ outp, int n) {
    int idx = blockIdx.x * blockDim.x + threadIdx.x;
    int total = n * 32;
    if (idx < total) {
        int nn = idx >> 5, c = idx & 31;
        float d = dis2[nn];
        float v = agg[idx] + d * d * y[idx] + ((c < 16) ? bmu[c] : bls[c - 16]);
        size_t o = (c < 16) ? ((size_t)nn * 16 + c)
                            : ((size_t)n * 16 + (size_t)nn * 16 + (c - 16));
        outp[o] = v;
    }
}

// ------------------------------------------------------------------ launch

extern "C" void kernel_launch(void* const* d_in, const int* in_sizes, int n_in,
                              void* d_out, int out_size, void* d_ws, size_t ws_size,
                              hipStream_t stream) {
    const float* x   = (const float*)d_in[0];
    const int*   ei  = (const int*)d_in[1];
    const float* W1  = (const float*)d_in[2];
    const float* b1  = (const float*)d_in[3];
    const float* W2  = (const float*)d_in[4];
    const float* b2  = (const float*)d_in[5];
    const float* Wmu = (const float*)d_in[6];
    const float* bmu = (const float*)d_in[7];
    const float* Wls = (const float*)d_in[8];
    const float* bls = (const float*)d_in[9];
    float* out = (float*)d_out;

    const int N = NN, E = EE;
    const int* row = ei;
    const int* col = ei + E;

    // workspace carve-up (256B aligned)
    char* p = (char*)d_ws;
    auto alloc = [&](size_t bytes) -> char* {
        char* r = p;
        p += (bytes + 255) & ~(size_t)255;
        return r;
    };
    int*   deg     = (int*)alloc((size_t)N * 4);
    int*   off     = (int*)alloc((size_t)(N + 1) * 4);
    int*   cursor  = (int*)alloc((size_t)N * 4);
    int*   csr_src = (int*)alloc((size_t)E * 4);
    float* wTag    = (float*)alloc((size_t)E * 4);
    float* wGcn    = (float*)alloc((size_t)E * 4);
    float* dis     = (float*)alloc((size_t)N * 4);
    float* dis2    = (float*)alloc((size_t)N * 4);
    float* hA      = (float*)alloc((size_t)N * CIN * 4);
    float* hB      = (float*)alloc((size_t)N * CIN * 4);
    float* o1      = (float*)alloc((size_t)N * L1C * 4);
    float* o2      = (float*)alloc((size_t)N * L2C * 4);

    const int B = 256;
    int gN = (N + B - 1) / B;
    int gE = (E + B - 1) / B;

    // --- graph preprocessing -> CSR by destination
    zero_int_kernel<<<gN, B, 0, stream>>>(deg, N);
    hist_kernel<<<gE, B, 0, stream>>>(col, deg, E);
    scan_kernel<<<1, 1024, 0, stream>>>(deg, off, N);
    dis_kernel<<<gN, B, 0, stream>>>(deg, dis, dis2, N);
    copy_int_kernel<<<gN, B, 0, stream>>>(off, cursor, N);
    fill_kernel<<<gE, B, 0, stream>>>(row, col, dis, dis2, cursor, csr_src, wTag, wGcn, E);

    // helpers for launches
    auto mm_grid = [&](int Cout) { return (((N + 3) / 4) * Cout + B - 1) / B; };
    size_t lds1 = (size_t)CIN * L1C * 4;  // 26880 B
    size_t lds2 = (size_t)L1C * L2C * 4;  // 12040 B

    int gAgg96 = (N * (CIN / 4) + B - 1) / B;
    int gAgg70 = (N * (L1C / 2) + B - 1) / B;
    int gAgg32 = (N * (32 / 4) + B - 1) / B;

    // --- TAG layer 1: o1 = b1 + x@W1[0] + h1@W1[1] + h2@W1[2] + h3@W1[3], relu
    mm_kernel<true, false><<<mm_grid(L1C), B, lds1, stream>>>(x, W1, b1, o1, N, CIN, L1C);
    agg_kernel<CIN, 4><<<gAgg96, B, 0, stream>>>(x, hA, off, csr_src, wTag, N);
    mm_kernel<false, false><<<mm_grid(L1C), B, lds1, stream>>>(hA, W1 + 1 * CIN * L1C, b1, o1, N, CIN, L1C);
    agg_kernel<CIN, 4><<<gAgg96, B, 0, stream>>>(hA, hB, off, csr_src, wTag, N);
    mm_kernel<false, false><<<mm_grid(L1C), B, lds1, stream>>>(hB, W1 + 2 * CIN * L1C, b1, o1, N, CIN, L1C);
    agg_kernel<CIN, 4><<<gAgg96, B, 0, stream>>>(hB, hA, off, csr_src, wTag, N);
    mm_kernel<false, true><<<mm_grid(L1C), B, lds1, stream>>>(hA, W1 + 3 * CIN * L1C, b1, o1, N, CIN, L1C);

    // --- TAG layer 2: o2 = b2 + o1@W2[0] + ... , relu   (o1 is x2 after relu)
    mm_kernel<true, false><<<mm_grid(L2C), B, lds2, stream>>>(o1, W2, b2, o2, N, L1C, L2C);
    agg_kernel<L1C, 2><<<gAgg70, B, 0, stream>>>(o1, hA, off, csr_src, wTag, N);
    mm_kernel<false, false><<<mm_grid(L2C), B, lds2, stream>>>(hA, W2 + 1 * L1C * L2C, b2, o2, N, L1C, L2C);
    agg_kernel<L1C, 2><<<gAgg70, B, 0, stream>>>(hA, hB, off, csr_src, wTag, N);
    mm_kernel<false, false><<<mm_grid(L2C), B, lds2, stream>>>(hB, W2 + 2 * L1C * L2C, b2, o2, N, L1C, L2C);
    agg_kernel<L1C, 2><<<gAgg70, B, 0, stream>>>(hB, hA, off, csr_src, wTag, N);
    mm_kernel<false, true><<<mm_grid(L2C), B, lds2, stream>>>(hA, W2 + 3 * L1C * L2C, b2, o2, N, L1C, L2C);

    // --- GCN heads: y = [o2@Wmu | o2@Wls] (N,32) in hA; agg with GCN norm in hB
    int gy = (N * 32 + B - 1) / B;
    y_kernel<<<gy, B, 0, stream>>>(o2, Wmu, Wls, hA, N);
    agg_kernel<32, 4><<<gAgg32, B, 0, stream>>>(hA, hB, off, csr_src, wGcn, N);
    final_kernel<<<gy, B, 0, stream>>>(hB, hA, dis2, bmu, bls, out, N);
}

// Round 2
// 783.487 us; speedup vs baseline: 1.3033x; 1.3033x over previous
//
#include <hip/hip_runtime.h>

// Problem constants (fixed by the reference)
static constexpr int NN  = 50000;   // nodes
static constexpr int EE  = 800000;  // edges
static constexpr int CIN = 96;      // input channels
static constexpr int L1C = 70;      // TAG layer 1 out
static constexpr int L2C = 43;      // TAG layer 2 out

// ---------------------------------------------------------------- preprocessing

// in-degree histogram over col
__global__ void hist_kernel(const int* __restrict__ col, int* __restrict__ deg, int E) {
    int e = blockIdx.x * blockDim.x + threadIdx.x;
    if (e < E) atomicAdd(&deg[col[e]], 1);
}

static constexpr int SB = 256;  // scan block size

// phase 1: per-block sums
__global__ void reduce_kernel(const int* __restrict__ deg, int* __restrict__ bsum, int n) {
    __shared__ int sd[SB];
    int i = blockIdx.x * SB + threadIdx.x;
    sd[threadIdx.x] = (i < n) ? deg[i] : 0;
    __syncthreads();
    for (int s = SB / 2; s > 0; s >>= 1) {
        if (threadIdx.x < s) sd[threadIdx.x] += sd[threadIdx.x + s];
        __syncthreads();
    }
    if (threadIdx.x == 0) bsum[blockIdx.x] = sd[0];
}

// phase 2: exclusive scan of block sums (nb <= 256), single block
__global__ void scan_sums_kernel(int* __restrict__ bsum, int nb) {
    __shared__ int sd[SB];
    int v = (threadIdx.x < nb) ? bsum[threadIdx.x] : 0;
    sd[threadIdx.x] = v;
    __syncthreads();
    for (int s = 1; s < SB; s <<= 1) {
        int t = (threadIdx.x >= s) ? sd[threadIdx.x - s] : 0;
        __syncthreads();
        sd[threadIdx.x] += t;
        __syncthreads();
    }
    if (threadIdx.x < nb) bsum[threadIdx.x] = sd[threadIdx.x] - v;  // exclusive
}

// phase 3: per-block exclusive scan + block offset; also emit cursor, dis, dis2
__global__ void block_scan_kernel(const int* __restrict__ deg, const int* __restrict__ bsum,
                                  int* __restrict__ off, int* __restrict__ cursor,
                                  float* __restrict__ dis, float* __restrict__ dis2, int n) {
    __shared__ int sd[SB];
    int i = blockIdx.x * SB + threadIdx.x;
    int v = (i < n) ? deg[i] : 0;
    sd[threadIdx.x] = v;
    __syncthreads();
    for (int s = 1; s < SB; s <<= 1) {
        int t = (threadIdx.x >= s) ? sd[threadIdx.x - s] : 0;
        __syncthreads();
        sd[threadIdx.x] += t;
        __syncthreads();
    }
    if (i < n) {
        int e = bsum[blockIdx.x] + sd[threadIdx.x] - v;
        off[i] = e;
        cursor[i] = e;
        dis[i]  = (v > 0) ? rsqrtf((float)v) : 0.0f;
        dis2[i] = rsqrtf((float)v + 1.0f);
        if (i == n - 1) off[n] = e + v;
    }
}

// place each edge into its destination bucket; store source + both edge weights
__global__ void fill_kernel(const int* __restrict__ row, const int* __restrict__ col,
                            const float* __restrict__ dis, const float* __restrict__ dis2,
                            int* __restrict__ cursor, int* __restrict__ csr_src,
                            float* __restrict__ wTag, float* __restrict__ wGcn, int E) {
    int e = blockIdx.x * blockDim.x + threadIdx.x;
    if (e < E) {
        int r = row[e], c = col[e];
        int pos = atomicAdd(&cursor[c], 1);
        csr_src[pos] = r;
        wTag[pos] = dis[r]  * dis[c];
        wGcn[pos] = dis2[r] * dis2[c];
    }
}

// ------------------------------------------------------------- aggregation
// out[i][c] = sum over incoming edges (w * in[src][c]); gather-based, no atomics.
template <int C, int VEC>
__global__ void agg_kernel(const float* __restrict__ in, float* __restrict__ out,
                           const int* __restrict__ off, const int* __restrict__ src,
                           const float* __restrict__ wgt, int n) {
    constexpr int TPN = C / VEC;          // threads per node
    int total = n * TPN;
    for (int t = blockIdx.x * blockDim.x + threadIdx.x; t < total;
         t += gridDim.x * blockDim.x) {
        int node = t / TPN;
        int cc = (t - node * TPN) * VEC;
        int beg = off[node], end = off[node + 1];
        if constexpr (VEC == 4) {
            float4 acc = make_float4(0.f, 0.f, 0.f, 0.f);
            for (int e = beg; e < end; ++e) {
                int s = src[e];
                float w = wgt[e];
                float4 v = *reinterpret_cast<const float4*>(in + s * C + cc);
                acc.x += w * v.x; acc.y += w * v.y;
                acc.z += w * v.z; acc.w += w * v.w;
            }
            *reinterpret_cast<float4*>(out + node * C + cc) = acc;
        } else {
            float2 acc = make_float2(0.f, 0.f);
            for (int e = beg; e < end; ++e) {
                int s = src[e];
                float w = wgt[e];
                float2 v = *reinterpret_cast<const float2*>(in + s * C + cc);
                acc.x += w * v.x; acc.y += w * v.y;
            }
            *reinterpret_cast<float2*>(out + node * C + cc) = acc;
        }
    }
}

// ----------------------------------------------------------------- matmul
// out[node, c0..c0+3] (+)= X[node, :] @ W[:, c0..c0+3]
// W staged in LDS padded to a multiple of 4 columns -> ds_read_b128.
// X row loads vectorized (float4 if CIN_%4==0, float2 if even, else scalar).
template <int CIN_, int COUT_, bool INIT, bool RELU>
__global__ void mm4_kernel(const float* __restrict__ X, const float* __restrict__ W,
                           const float* __restrict__ bias, float* __restrict__ out, int n) {
    constexpr int CP4 = (COUT_ + 3) / 4;
    constexpr int PAD = CP4 * 4;
    __shared__ __align__(16) float Wl[CIN_ * PAD];
    __shared__ __align__(16) float bl[PAD];
    for (int i = threadIdx.x; i < CIN_ * PAD; i += blockDim.x) {
        int k = i / PAD, c = i - k * PAD;
        Wl[i] = (c < COUT_) ? W[k * COUT_ + c] : 0.f;
    }
    for (int i = threadIdx.x; i < PAD; i += blockDim.x)
        bl[i] = (i < COUT_) ? bias[i] : 0.f;
    __syncthreads();

    int total = n * CP4;
    for (int idx = blockIdx.x * blockDim.x + threadIdx.x; idx < total;
         idx += gridDim.x * blockDim.x) {
        int node = idx / CP4;
        int cg = idx - node * CP4;
        int c0 = cg * 4;
        const float* xr = X + (size_t)node * CIN_;
        float* orow = out + (size_t)node * COUT_ + c0;
        float4 acc;
        if constexpr (INIT) {
            acc = *reinterpret_cast<const float4*>(&bl[c0]);
        } else {
            acc.x = orow[0];
            acc.y = (c0 + 1 < COUT_) ? orow[1] : 0.f;
            acc.z = (c0 + 2 < COUT_) ? orow[2] : 0.f;
            acc.w = (c0 + 3 < COUT_) ? orow[3] : 0.f;
        }
        if constexpr (CIN_ % 4 == 0) {
            #pragma unroll 4
            for (int k4 = 0; k4 < CIN_ / 4; ++k4) {
                float4 xv = *reinterpret_cast<const float4*>(xr + k4 * 4);
                float4 w0 = *reinterpret_cast<const float4*>(&Wl[(k4 * 4 + 0) * PAD + c0]);
                float4 w1 = *reinterpret_cast<const float4*>(&Wl[(k4 * 4 + 1) * PAD + c0]);
                float4 w2 = *reinterpret_cast<const float4*>(&Wl[(k4 * 4 + 2) * PAD + c0]);
                float4 w3 = *reinterpret_cast<const float4*>(&Wl[(k4 * 4 + 3) * PAD + c0]);
                acc.x += xv.x * w0.x + xv.y * w1.x + xv.z * w2.x + xv.w * w3.x;
                acc.y += xv.x * w0.y + xv.y * w1.y + xv.z * w2.y + xv.w * w3.y;
                acc.z += xv.x * w0.z + xv.y * w1.z + xv.z * w2.z + xv.w * w3.z;
                acc.w += xv.x * w0.w + xv.y * w1.w + xv.z * w2.w + xv.w * w3.w;
            }
        } else if constexpr (CIN_ % 2 == 0) {
            #pragma unroll 4
            for (int k2 = 0; k2 < CIN_ / 2; ++k2) {
                float2 xv = *reinterpret_cast<const float2*>(xr + k2 * 2);
                float4 w0 = *reinterpret_cast<const float4*>(&Wl[(k2 * 2 + 0) * PAD + c0]);
                float4 w1 = *reinterpret_cast<const float4*>(&Wl[(k2 * 2 + 1) * PAD + c0]);
                acc.x += xv.x * w0.x + xv.y * w1.x;
                acc.y += xv.x * w0.y + xv.y * w1.y;
                acc.z += xv.x * w0.z + xv.y * w1.z;
                acc.w += xv.x * w0.w + xv.y * w1.w;
            }
        } else {
            #pragma unroll 4
            for (int k = 0; k < CIN_; ++k) {
                float xk = xr[k];
                float4 w = *reinterpret_cast<const float4*>(&Wl[k * PAD + c0]);
                acc.x += xk * w.x; acc.y += xk * w.y;
                acc.z += xk * w.z; acc.w += xk * w.w;
            }
        }
        if constexpr (RELU) {
            acc.x = fmaxf(acc.x, 0.f); acc.y = fmaxf(acc.y, 0.f);
            acc.z = fmaxf(acc.z, 0.f); acc.w = fmaxf(acc.w, 0.f);
        }
        orow[0] = acc.x;
        if (c0 + 1 < COUT_) orow[1] = acc.y;
        if (c0 + 2 < COUT_) orow[2] = acc.z;
        if (c0 + 3 < COUT_) orow[3] = acc.w;
    }
}

// y[n, 0:16] = x3 @ Wmu ; y[n, 16:32] = x3 @ Wls  (bias added in final kernel)
__global__ void y4_kernel(const float* __restrict__ X, const float* __restrict__ Wmu,
                          const float* __restrict__ Wls, float* __restrict__ y, int n) {
    __shared__ __align__(16) float Wl[L2C * 32];
    for (int i = threadIdx.x; i < L2C * 32; i += blockDim.x) {
        int k = i >> 5, c = i & 31;
        Wl[i] = (c < 16) ? Wmu[k * 16 + c] : Wls[k * 16 + (c - 16)];
    }
    __syncthreads();
    int total = n * 8;
    for (int idx = blockIdx.x * blockDim.x + threadIdx.x; idx < total;
         idx += gridDim.x * blockDim.x) {
        int nn = idx >> 3, c0 = (idx & 7) * 4;
        const float* xr = X + (size_t)nn * L2C;
        float4 acc = make_float4(0.f, 0.f, 0.f, 0.f);
        #pragma unroll 4
        for (int k = 0; k < L2C; ++k) {
            float xk = xr[k];
            float4 w = *reinterpret_cast<const float4*>(&Wl[k * 32 + c0]);
            acc.x += xk * w.x; acc.y += xk * w.y;
            acc.z += xk * w.z; acc.w += xk * w.w;
        }
        *reinterpret_cast<float4*>(y + (size_t)nn * 32 + c0) = acc;
    }
}

// out = agg + dis2^2 * y + bias ; split interleaved (N,32) -> mu (N,16) ++ logstd (N,16)
__global__ void final_kernel(const float* __restrict__ agg, const float* __restrict__ y,
                             const float* __restrict__ dis2, const float* __restrict__ bmu,
                             const float* __restrict__ bls, float* __restrict__ outp, int n) {
    int idx = blockIdx.x * blockDim.x + threadIdx.x;
    int total = n * 32;
    if (idx < total) {
        int nn = idx >> 5, c = idx & 31;
        float d = dis2[nn];
        float v = agg[idx] + d * d * y[idx] + ((c < 16) ? bmu[c] : bls[c - 16]);
        size_t o = (c < 16) ? ((size_t)nn * 16 + c)
                            : ((size_t)n * 16 + (size_t)nn * 16 + (c - 16));
        outp[o] = v;
    }
}

// ------------------------------------------------------------------ launch

extern "C" void kernel_launch(void* const* d_in, const int* in_sizes, int n_in,
                              void* d_out, int out_size, void* d_ws, size_t ws_size,
                              hipStream_t stream) {
    const float* x   = (const float*)d_in[0];
    const int*   ei  = (const int*)d_in[1];
    const float* W1  = (const float*)d_in[2];
    const float* b1  = (const float*)d_in[3];
    const float* W2  = (const float*)d_in[4];
    const float* b2  = (const float*)d_in[5];
    const float* Wmu = (const float*)d_in[6];
    const float* bmu = (const float*)d_in[7];
    const float* Wls = (const float*)d_in[8];
    const float* bls = (const float*)d_in[9];
    float* out = (float*)d_out;

    const int N = NN, E = EE;
    const int* row = ei;
    const int* col = ei + E;

    // workspace carve-up (256B aligned)
    char* p = (char*)d_ws;
    auto alloc = [&](size_t bytes) -> char* {
        char* r = p;
        p += (bytes + 255) & ~(size_t)255;
        return r;
    };
    int*   deg     = (int*)alloc((size_t)N * 4);
    int*   off     = (int*)alloc((size_t)(N + 1) * 4);
    int*   cursor  = (int*)alloc((size_t)N * 4);
    int*   bsum    = (int*)alloc((size_t)256 * 4);
    int*   csr_src = (int*)alloc((size_t)E * 4);
    float* wTag    = (float*)alloc((size_t)E * 4);
    float* wGcn    = (float*)alloc((size_t)E * 4);
    float* dis     = (float*)alloc((size_t)N * 4);
    float* dis2    = (float*)alloc((size_t)N * 4);
    float* hA      = (float*)alloc((size_t)N * CIN * 4);
    float* hB      = (float*)alloc((size_t)N * CIN * 4);
    float* o1      = (float*)alloc((size_t)N * L1C * 4);
    float* o2      = (float*)alloc((size_t)N * L2C * 4);

    const int B = 256;
    int gE = (E + B - 1) / B;
    int nb = (N + SB - 1) / SB;  // 196 scan blocks

    // --- graph preprocessing -> CSR by destination
    hipMemsetAsync(deg, 0, (size_t)N * 4, stream);
    hist_kernel<<<gE, B, 0, stream>>>(col, deg, E);
    reduce_kernel<<<nb, SB, 0, stream>>>(deg, bsum, N);
    scan_sums_kernel<<<1, SB, 0, stream>>>(bsum, nb);
    block_scan_kernel<<<nb, SB, 0, stream>>>(deg, bsum, off, cursor, dis, dis2, N);
    fill_kernel<<<gE, B, 0, stream>>>(row, col, dis, dis2, cursor, csr_src, wTag, wGcn, E);

    // helpers for launches
    auto g4 = [&](int cp4) { return (N * cp4 + B - 1) / B; };
    int gm1 = g4((L1C + 3) / 4);  // 18 channel groups
    int gm2 = g4((L2C + 3) / 4);  // 11 channel groups

    int gAgg96 = (N * (CIN / 4) + B - 1) / B;
    int gAgg70 = (N * (L1C / 2) + B - 1) / B;
    int gAgg32 = (N * (32 / 4) + B - 1) / B;

    // --- TAG layer 1: o1 = b1 + x@W1[0] + h1@W1[1] + h2@W1[2] + h3@W1[3], relu
    mm4_kernel<CIN, L1C, true,  false><<<gm1, B, 0, stream>>>(x,  W1,                 b1, o1, N);
    agg_kernel<CIN, 4><<<gAgg96, B, 0, stream>>>(x,  hA, off, csr_src, wTag, N);
    mm4_kernel<CIN, L1C, false, false><<<gm1, B, 0, stream>>>(hA, W1 + 1 * CIN * L1C, b1, o1, N);
    agg_kernel<CIN, 4><<<gAgg96, B, 0, stream>>>(hA, hB, off, csr_src, wTag, N);
    mm4_kernel<CIN, L1C, false, false><<<gm1, B, 0, stream>>>(hB, W1 + 2 * CIN * L1C, b1, o1, N);
    agg_kernel<CIN, 4><<<gAgg96, B, 0, stream>>>(hB, hA, off, csr_src, wTag, N);
    mm4_kernel<CIN, L1C, false, true ><<<gm1, B, 0, stream>>>(hA, W1 + 3 * CIN * L1C, b1, o1, N);

    // --- TAG layer 2: o2 = b2 + o1@W2[0] + ... , relu
    mm4_kernel<L1C, L2C, true,  false><<<gm2, B, 0, stream>>>(o1, W2,                 b2, o2, N);
    agg_kernel<L1C, 2><<<gAgg70, B, 0, stream>>>(o1, hA, off, csr_src, wTag, N);
    mm4_kernel<L1C, L2C, false, false><<<gm2, B, 0, stream>>>(hA, W2 + 1 * L1C * L2C, b2, o2, N);
    agg_kernel<L1C, 2><<<gAgg70, B, 0, stream>>>(hA, hB, off, csr_src, wTag, N);
    mm4_kernel<L1C, L2C, false, false><<<gm2, B, 0, stream>>>(hB, W2 + 2 * L1C * L2C, b2, o2, N);
    agg_kernel<L1C, 2><<<gAgg70, B, 0, stream>>>(hB, hA, off, csr_src, wTag, N);
    mm4_kernel<L1C, L2C, false, true ><<<gm2, B, 0, stream>>>(hA, W2 + 3 * L1C * L2C, b2, o2, N);

    // --- GCN heads: y = [o2@Wmu | o2@Wls] (N,32) in hA; agg with GCN norm in hB
    int gy = (N * 32 + B - 1) / B;
    y4_kernel<<<(N * 8 + B - 1) / B, B, 0, stream>>>(o2, Wmu, Wls, hA, N);
    agg_kernel<32, 4><<<gAgg32, B, 0, stream>>>(hA, hB, off, csr_src, wGcn, N);
    final_kernel<<<gy, B, 0, stream>>>(hB, hA, dis2, bmu, bls, out, N);
}